// Round 3
// baseline (152.402 us; speedup 1.0000x reference)
//
#include <hip/hip_runtime.h>
#include <hip/hip_bf16.h>
#include <stdint.h>

// VSN: B=16,T=256 -> NTOK=4096 tokens, V=64 vars, H=256 hidden.
#define NTOK 4096
#define NV 64
#define NH 256
#define LN_EPS 1e-5f

typedef __attribute__((ext_vector_type(8))) short short8;
typedef __attribute__((ext_vector_type(4))) float f32x4;
typedef __attribute__((ext_vector_type(4))) uint32_t u32x4;

__device__ __forceinline__ unsigned short f32_to_bf16(float f) {
    uint32_t u = __builtin_bit_cast(uint32_t, f);
    return (unsigned short)((u + 0x7FFFu + ((u >> 16) & 1u)) >> 16);  // RNE
}
__device__ __forceinline__ float fsigmoid(float z) { return 1.0f / (1.0f + __expf(-z)); }
__device__ __forceinline__ float felu(float z) { return z > 0.0f ? z : (__expf(z) - 1.0f); }
// pack two f32 -> bf16x2 (round-half-up) in 3 ops: 2 adds + v_perm
__device__ __forceinline__ uint32_t pack_bf16x2(float ze, float zo) {
    const uint32_t ue = __builtin_bit_cast(uint32_t, ze) + 0x8000u;
    const uint32_t uo = __builtin_bit_cast(uint32_t, zo) + 0x8000u;
    return __builtin_amdgcn_perm(uo, ue, 0x07060302u);  // (hi16(uo)<<16)|hi16(ue)
}
__device__ __forceinline__ void gload16(const void* g, void* l) {
    __builtin_amdgcn_global_load_lds(
        (const __attribute__((address_space(1))) uint32_t*)g,
        (__attribute__((address_space(3))) uint32_t*)l, 16, 0, 0);
}

// ---------------- Kernel A: W2 [v][h][o] f32 -> W2T [v][o][h] bf16 ----------------
__global__ __launch_bounds__(256) void k_w2t(const float* __restrict__ W2,
                                             unsigned short* __restrict__ W2T) {
    __shared__ float tile[32][33];
    const int v  = blockIdx.x >> 6;
    const int t  = blockIdx.x & 63;
    const int h0 = (t & 7) * 32;
    const int o0 = (t >> 3) * 32;
    const int r  = threadIdx.x >> 3;
    const int c4 = (threadIdx.x & 7) * 4;
    const float4 d = *(const float4*)(W2 + ((size_t)v * NH + h0 + r) * NH + o0 + c4);
    tile[r][c4 + 0] = d.x; tile[r][c4 + 1] = d.y;
    tile[r][c4 + 2] = d.z; tile[r][c4 + 3] = d.w;
    __syncthreads();
    ushort4 o;
    o.x = f32_to_bf16(tile[c4 + 0][r]);
    o.y = f32_to_bf16(tile[c4 + 1][r]);
    o.z = f32_to_bf16(tile[c4 + 2][r]);
    o.w = f32_to_bf16(tile[c4 + 3][r]);
    *(ushort4*)(W2T + ((size_t)v * NH + o0 + r) * NH + h0 + c4) = o;
}

// ---------------- Kernel B: weight-network GRN + softmax -> weights[tok][v] -------
__global__ __launch_bounds__(256) void k_weights(
    const float* __restrict__ x,
    const float* __restrict__ nW1, const float* __restrict__ nb1,
    const float* __restrict__ nW2, const float* __restrict__ nb2,
    const float* __restrict__ nWg, const float* __restrict__ nbg,
    const float* __restrict__ ng,  const float* __restrict__ nbe,
    float* __restrict__ wout_buf) {
    const int wv = threadIdx.x >> 6;
    const int lane = threadIdx.x & 63;
    const int tok = blockIdx.x * 4 + wv;
    const float xv = x[(size_t)tok * NV + lane];
    float acc1 = nb1[lane], accg = nbg[lane];
#pragma unroll 8
    for (int k = 0; k < 64; ++k) {
        const float xk = __shfl(xv, k);
        acc1 = fmaf(xk, nW1[k * 64 + lane], acc1);
        accg = fmaf(xk, nWg[k * 64 + lane], accg);
    }
    const float h  = felu(acc1);
    const float wg = fsigmoid(accg);
    float acc2 = nb2[lane];
#pragma unroll 8
    for (int k = 0; k < 64; ++k) {
        const float hk = __shfl(h, k);
        acc2 = fmaf(hk, nW2[k * 64 + lane], acc2);
    }
    const float pre = xv + wg * acc2;
    float s = pre;
#pragma unroll
    for (int m = 32; m >= 1; m >>= 1) s += __shfl_xor(s, m);
    const float mu = s * (1.0f / 64.0f);
    const float dd = pre - mu;
    float s2 = dd * dd;
#pragma unroll
    for (int m = 32; m >= 1; m >>= 1) s2 += __shfl_xor(s2, m);
    const float inv = rsqrtf(s2 * (1.0f / 64.0f) + LN_EPS);
    const float wln = dd * inv * ng[lane] + nbe[lane];
    float mx = wln;
#pragma unroll
    for (int m = 32; m >= 1; m >>= 1) mx = fmaxf(mx, __shfl_xor(mx, m));
    const float e = __expf(wln - mx);
    float se = e;
#pragma unroll
    for (int m = 32; m >= 1; m >>= 1) se += __shfl_xor(se, m);
    wout_buf[(size_t)tok * NV + lane] = e / se;
}

__device__ __forceinline__ const float* row_ptr(int r, const float* W1, const float* b1,
                                                const float* Wg, const float* bg,
                                                const float* Ws, const float* bs,
                                                const float* b2, const float* g1,
                                                const float* be1) {
    switch (r) {
        case 0: return W1; case 1: return b1; case 2: return Wg; case 3: return bg;
        case 4: return Ws; case 5: return bs; case 6: return b2; case 7: return g1;
        default: return be1;
    }
}

// ---------------- Kernel C: fused per-var GRN (MFMA) + weighted accumulate --------
// grid 512 (bid&7 = vgroup -> XCD affinity; bid>>3 = 64-token tile). 256 thr =
// 4 waves = 2 token-groups x 2 H-halves; wave = 32 tok x 128 H. LDS ~56KB ->
// 2 blocks/CU: two independent barrier domains overlap each other's drains.
// vi/ks loops kept rolled (#pragma unroll 1) to keep the body I$-resident.
__global__ __launch_bounds__(256, 2) void k_main(
    const float* __restrict__ x, const unsigned short* __restrict__ W2T,
    const float* __restrict__ W1, const float* __restrict__ b1,
    const float* __restrict__ Wg, const float* __restrict__ bg,
    const float* __restrict__ Ws, const float* __restrict__ bs,
    const float* __restrict__ b2, const float* __restrict__ g1,
    const float* __restrict__ be1, const float* __restrict__ wgts,
    float* __restrict__ partials,   // [8][NTOK][NH] or nullptr
    float* __restrict__ outacc) {   // atomic fallback
    __shared__ u32x4 sB[2][1024];     // 2 x 16KB B K-step panel, slot-swizzled
    __shared__ float sRB[2][9][256];  // 2 x {W1,b1,Wg,bg,Ws,bs,b2,g1,be1}
    __shared__ float sX[64][9];       // [tok][var] (+pad)
    __shared__ float sW[64][9];
    __shared__ float sLN[64][2][2];   // [tok][hh][ps,pq]

    const int tid  = threadIdx.x;
    const int wid  = tid >> 6, lane = tid & 63;
    const int c    = lane & 15, kg = lane >> 4;
    const int tg   = wid >> 1, hh = wid & 1;
    const int bid  = blockIdx.x;
    const int vg   = bid & 7, tt = bid >> 3;
    const int t0   = tt * 64, vbase = vg * 8;

    const float* r0p = row_ptr(2 * wid,     W1, b1, Wg, bg, Ws, bs, b2, g1, be1);
    const float* r1p = row_ptr(2 * wid + 1, W1, b1, Wg, bg, Ws, bs, b2, g1, be1);

    // ---- prologue ----
    const unsigned short* W2Tv0 = W2T + (size_t)vbase * (NH * NH);
#pragma unroll
    for (int q = 0; q < 4; ++q) {   // B(v=vbase, ks=0) -> sB[0]
        const int idx = wid * 256 + q * 64 + lane;
        const int o = idx >> 2, sl = idx & 3;
        const int s = (sl - (o >> 1)) & 3;
        gload16(W2Tv0 + (size_t)o * NH + s * 8,
                (char*)sB[0] + (size_t)(wid * 256 + q * 64) * 16);
    }
    gload16(r0p + (size_t)vbase * NH + lane * 4, (char*)sRB[0] + (2 * wid) * 1024);
    gload16(r1p + (size_t)vbase * NH + lane * 4, (char*)sRB[0] + (2 * wid + 1) * 1024);
    if (wid == 0)
        gload16(be1 + (size_t)vbase * NH + lane * 4, (char*)sRB[0] + 8 * 1024);
#pragma unroll
    for (int e = 0; e < 2; ++e) {
        const int ee = tid + e * 256;
        const int row = ee >> 3, cc = ee & 7;
        sX[row][cc] = x[(size_t)(t0 + row) * NV + vbase + cc];
        sW[row][cc] = wgts[(size_t)(t0 + row) * NV + vbase + cc];
    }
    __syncthreads();

    // b128 B-frag read base: row o = (hh*8+f)*16+c, slot rotated -> balanced banks
    const int rdbase = hh * 8192 + c * 64 + (((kg + (c >> 1)) & 3) << 4);
    const f32x4 fzero = {0.f, 0.f, 0.f, 0.f};

    f32x4 wacc[2][8];
#pragma unroll
    for (int rt = 0; rt < 2; ++rt)
#pragma unroll
        for (int f = 0; f < 8; ++f) wacc[rt][f] = fzero;

#pragma unroll 1
    for (int vi = 0; vi < 8; ++vi) {
        const int rcur = vi & 1;
        const unsigned short* W2Tv = W2T + (size_t)(vbase + vi) * (NH * NH);
        const float xv0 = sX[tg * 32 + c][vi];
        const float xv1 = sX[tg * 32 + 16 + c][vi];

        f32x4 acc[2][8];
#pragma unroll
        for (int rt = 0; rt < 2; ++rt)
#pragma unroll
            for (int f = 0; f < 8; ++f) acc[rt][f] = fzero;

#pragma unroll 1
        for (int ks = 0; ks < 8; ++ks) {
            const int cb = ks & 1;
            // -- prefetch next var's param rows (once per var) --
            if (ks == 0 && vi < 7) {
                gload16(r0p + (size_t)(vbase + vi + 1) * NH + lane * 4,
                        (char*)sRB[rcur ^ 1] + (2 * wid) * 1024);
                gload16(r1p + (size_t)(vbase + vi + 1) * NH + lane * 4,
                        (char*)sRB[rcur ^ 1] + (2 * wid + 1) * 1024);
                if (wid == 0)
                    gload16(be1 + (size_t)(vbase + vi + 1) * NH + lane * 4,
                            (char*)sRB[rcur ^ 1] + 8 * 1024);
            }
            // -- prefetch next B panel --
            if (ks < 7 || vi < 7) {
                const unsigned short* Wsrc = (ks < 7) ? W2Tv : (W2Tv + NH * NH);
                const int ksn = (ks < 7) ? (ks + 1) : 0;
#pragma unroll
                for (int q = 0; q < 4; ++q) {
                    const int idx = wid * 256 + q * 64 + lane;
                    const int o = idx >> 2, sl = idx & 3;
                    const int s = (sl - (o >> 1)) & 3;
                    gload16(Wsrc + (size_t)o * NH + ksn * 32 + s * 8,
                            (char*)sB[cb ^ 1] + (size_t)(wid * 256 + q * 64) * 16);
                }
            }
            // -- A-frag gen (2 row-tiles) --
            const int k0 = ks * 32 + kg * 8;
            const float4 wA = *(const float4*)&sRB[rcur][0][k0];
            const float4 wB = *(const float4*)&sRB[rcur][0][k0 + 4];
            const float4 bA = *(const float4*)&sRB[rcur][1][k0];
            const float4 bB = *(const float4*)&sRB[rcur][1][k0 + 4];
            u32x4 ap0, ap1;
            {
                const float z0 = fmaf(xv0, wA.x, bA.x), z1 = fmaf(xv0, wA.y, bA.y);
                const float z2 = fmaf(xv0, wA.z, bA.z), z3 = fmaf(xv0, wA.w, bA.w);
                const float z4 = fmaf(xv0, wB.x, bB.x), z5 = fmaf(xv0, wB.y, bB.y);
                const float z6 = fmaf(xv0, wB.z, bB.z), z7 = fmaf(xv0, wB.w, bB.w);
                ap0[0] = pack_bf16x2(felu(z0), felu(z1));
                ap0[1] = pack_bf16x2(felu(z2), felu(z3));
                ap0[2] = pack_bf16x2(felu(z4), felu(z5));
                ap0[3] = pack_bf16x2(felu(z6), felu(z7));
            }
            {
                const float z0 = fmaf(xv1, wA.x, bA.x), z1 = fmaf(xv1, wA.y, bA.y);
                const float z2 = fmaf(xv1, wA.z, bA.z), z3 = fmaf(xv1, wA.w, bA.w);
                const float z4 = fmaf(xv1, wB.x, bB.x), z5 = fmaf(xv1, wB.y, bB.y);
                const float z6 = fmaf(xv1, wB.z, bB.z), z7 = fmaf(xv1, wB.w, bB.w);
                ap1[0] = pack_bf16x2(felu(z0), felu(z1));
                ap1[1] = pack_bf16x2(felu(z2), felu(z3));
                ap1[2] = pack_bf16x2(felu(z4), felu(z5));
                ap1[3] = pack_bf16x2(felu(z6), felu(z7));
            }
            const short8 af0 = __builtin_bit_cast(short8, ap0);
            const short8 af1 = __builtin_bit_cast(short8, ap1);
            const char* bb = (const char*)sB[cb] + rdbase;
            __builtin_amdgcn_s_setprio(1);
#pragma unroll
            for (int f = 0; f < 8; ++f) {
                const short8 bf = __builtin_bit_cast(short8, *(const u32x4*)(bb + (f << 10)));
                acc[0][f] = __builtin_amdgcn_mfma_f32_16x16x32_bf16(af0, bf, acc[0][f], 0, 0, 0);
                acc[1][f] = __builtin_amdgcn_mfma_f32_16x16x32_bf16(af1, bf, acc[1][f], 0, 0, 0);
            }
            __builtin_amdgcn_s_setprio(0);
            __syncthreads();   // drains prefetch + buffer swap
        }

        // -- epilogue: gate/skip/sigmoid, cross-wave LN, weighted accumulate --
        float xr[2][4], wv_[2][4], gv[8], bev[8];
#pragma unroll
        for (int rt = 0; rt < 2; ++rt)
#pragma unroll
            for (int r = 0; r < 4; ++r) {
                const int tl = tg * 32 + rt * 16 + kg * 4 + r;
                xr[rt][r]  = sX[tl][vi];
                wv_[rt][r] = sW[tl][vi];
            }
        float ps[2][4] = {}, pq[2][4] = {};
#pragma unroll
        for (int f = 0; f < 8; ++f) {
            const int h = ((hh << 3) + f) * 16 + c;
            const float Wg_ = sRB[rcur][2][h], bg_ = sRB[rcur][3][h];
            const float Ws_ = sRB[rcur][4][h], bs_ = sRB[rcur][5][h];
            const float b2_ = sRB[rcur][6][h];
            gv[f] = sRB[rcur][7][h]; bev[f] = sRB[rcur][8][h];
#pragma unroll
            for (int rt = 0; rt < 2; ++rt)
#pragma unroll
                for (int r = 0; r < 4; ++r) {
                    const float y = fmaf(xr[rt][r], Ws_, bs_) +
                                    fsigmoid(fmaf(xr[rt][r], Wg_, bg_)) * (acc[rt][f][r] + b2_);
                    acc[rt][f][r] = y;
                    ps[rt][r] += y;
                    pq[rt][r] = fmaf(y, y, pq[rt][r]);
                }
        }
#pragma unroll
        for (int m = 1; m <= 8; m <<= 1)
#pragma unroll
            for (int rt = 0; rt < 2; ++rt)
#pragma unroll
                for (int r = 0; r < 4; ++r) {
                    ps[rt][r] += __shfl_xor(ps[rt][r], m);
                    pq[rt][r] += __shfl_xor(pq[rt][r], m);
                }
        if (c == 0) {
#pragma unroll
            for (int rt = 0; rt < 2; ++rt)
#pragma unroll
                for (int r = 0; r < 4; ++r) {
                    const int tl = tg * 32 + rt * 16 + kg * 4 + r;
                    *(float2*)&sLN[tl][hh][0] = float2{ps[rt][r], pq[rt][r]};
                }
        }
        __syncthreads();  // sLN ready; also fences sRB[rcur] reads before overwrite
#pragma unroll
        for (int rt = 0; rt < 2; ++rt)
#pragma unroll
            for (int r = 0; r < 4; ++r) {
                const int tl = tg * 32 + rt * 16 + kg * 4 + r;
                const float4 q4 = *(const float4*)&sLN[tl][0][0];
                const float mu = (q4.x + q4.z) * (1.0f / 256.0f);
                const float vr = (q4.y + q4.w) * (1.0f / 256.0f) - mu * mu;
                const float iv = rsqrtf(vr + LN_EPS);
#pragma unroll
                for (int f = 0; f < 8; ++f)
                    wacc[rt][f][r] = fmaf(wv_[rt][r],
                                          fmaf((acc[rt][f][r] - mu) * iv, gv[f], bev[f]),
                                          wacc[rt][f][r]);
            }
    }

    // -- write per-vgroup partials --
    if (partials) {
        float* P = partials + (size_t)vg * NTOK * NH;
#pragma unroll
        for (int rt = 0; rt < 2; ++rt)
#pragma unroll
            for (int r = 0; r < 4; ++r) {
                float* rowp = P + (size_t)(t0 + tg * 32 + rt * 16 + kg * 4 + r) * NH + hh * 128 + c;
#pragma unroll
                for (int f = 0; f < 8; ++f) rowp[f * 16] = wacc[rt][f][r];
            }
    } else {
#pragma unroll
        for (int rt = 0; rt < 2; ++rt)
#pragma unroll
            for (int r = 0; r < 4; ++r) {
                float* rowp = outacc + (size_t)(t0 + tg * 32 + rt * 16 + kg * 4 + r) * NH + hh * 128 + c;
#pragma unroll
                for (int f = 0; f < 8; ++f) atomicAdd(&rowp[f * 16], wacc[rt][f][r]);
            }
    }
}

// ---------------- Kernel D: sum the 8 vgroup partials ----------------
__global__ __launch_bounds__(256) void k_reduce(const float* __restrict__ P,
                                                float* __restrict__ out) {
    const size_t i = ((size_t)blockIdx.x * 256 + threadIdx.x);
    const f32x4* P4 = (const f32x4*)P;
    f32x4 s = P4[i];
#pragma unroll
    for (int sl = 1; sl < 8; ++sl) s += P4[(size_t)sl * (NTOK * NH / 4) + i];
    ((f32x4*)out)[i] = s;
}

extern "C" void kernel_launch(void* const* d_in, const int* in_sizes, int n_in,
                              void* d_out, int out_size, void* d_ws, size_t ws_size,
                              hipStream_t stream) {
    const float* x   = (const float*)d_in[0];
    const float* W1  = (const float*)d_in[1];
    const float* b1  = (const float*)d_in[2];
    const float* W2  = (const float*)d_in[3];
    const float* b2  = (const float*)d_in[4];
    const float* Wg  = (const float*)d_in[5];
    const float* bg  = (const float*)d_in[6];
    const float* Ws  = (const float*)d_in[7];
    const float* bs  = (const float*)d_in[8];
    const float* g1  = (const float*)d_in[9];
    const float* be1 = (const float*)d_in[10];
    const float* nW1 = (const float*)d_in[11];
    const float* nb1 = (const float*)d_in[12];
    const float* nW2 = (const float*)d_in[13];
    const float* nb2 = (const float*)d_in[14];
    const float* nWg = (const float*)d_in[15];
    const float* nbg = (const float*)d_in[16];
    const float* ng  = (const float*)d_in[17];
    const float* nbe = (const float*)d_in[18];
    float* out = (float*)d_out;

    // ws layout: [0,1MB) weights | [1MB,9MB) W2T bf16 | [9MB,41MB) partials
    char* ws = (char*)d_ws;
    float* ws_wgt = (float*)ws;
    unsigned short* ws_W2T = (unsigned short*)(ws + (1 << 20));
    const size_t part_off = (size_t)9 << 20;
    const size_t part_bytes = (size_t)8 * NTOK * NH * 4;
    const bool use_part = ws_size >= part_off + part_bytes;
    float* ws_part = use_part ? (float*)(ws + part_off) : nullptr;

    k_w2t<<<dim3(64 * 64), dim3(256), 0, stream>>>(W2, ws_W2T);
    k_weights<<<dim3(NTOK / 4), dim3(256), 0, stream>>>(x, nW1, nb1, nW2, nb2,
                                                        nWg, nbg, ng, nbe, ws_wgt);
    if (!use_part) hipMemsetAsync(d_out, 0, (size_t)out_size * 4, stream);
    k_main<<<dim3(512), dim3(256), 0, stream>>>(x, ws_W2T, W1, b1, Wg, bg, Ws, bs,
                                                b2, g1, be1, ws_wgt, ws_part, out);
    if (use_part)
        k_reduce<<<dim3(NTOK * NH / 4 / 256), dim3(256), 0, stream>>>(ws_part, out);
}

// Round 4
// 143.487 us; speedup vs baseline: 1.0621x; 1.0621x over previous
//
#include <hip/hip_runtime.h>
#include <hip/hip_bf16.h>
#include <stdint.h>

// VSN: B=16,T=256 -> NTOK=4096 tokens, V=64 vars, H=256 hidden.
#define NTOK 4096
#define NV 64
#define NH 256
#define LN_EPS 1e-5f

typedef __attribute__((ext_vector_type(8))) short short8;
typedef __attribute__((ext_vector_type(4))) float f32x4;
typedef __attribute__((ext_vector_type(4))) uint32_t u32x4;

__device__ __forceinline__ unsigned short f32_to_bf16(float f) {
    uint32_t u = __builtin_bit_cast(uint32_t, f);
    return (unsigned short)((u + 0x7FFFu + ((u >> 16) & 1u)) >> 16);  // RNE
}
__device__ __forceinline__ float fsigmoid(float z) { return 1.0f / (1.0f + __expf(-z)); }
__device__ __forceinline__ float felu(float z) { return z > 0.0f ? z : (__expf(z) - 1.0f); }
// pack two f32 -> bf16x2 (round-half-up) in 3 ops: 2 adds + v_perm
__device__ __forceinline__ uint32_t pack_bf16x2(float ze, float zo) {
    const uint32_t ue = __builtin_bit_cast(uint32_t, ze) + 0x8000u;
    const uint32_t uo = __builtin_bit_cast(uint32_t, zo) + 0x8000u;
    return __builtin_amdgcn_perm(uo, ue, 0x07060302u);  // (hi16(uo)<<16)|hi16(ue)
}
__device__ __forceinline__ void gload16(const void* g, void* l) {
    __builtin_amdgcn_global_load_lds(
        (const __attribute__((address_space(1))) uint32_t*)g,
        (__attribute__((address_space(3))) uint32_t*)l, 16, 0, 0);
}

// ---------------- Kernel A: W2 [v][h][o] f32 -> W2T [v][o][h] bf16 ----------------
__global__ __launch_bounds__(256) void k_w2t(const float* __restrict__ W2,
                                             unsigned short* __restrict__ W2T) {
    __shared__ float tile[32][33];
    const int v  = blockIdx.x >> 6;
    const int t  = blockIdx.x & 63;
    const int h0 = (t & 7) * 32;
    const int o0 = (t >> 3) * 32;
    const int r  = threadIdx.x >> 3;
    const int c4 = (threadIdx.x & 7) * 4;
    const float4 d = *(const float4*)(W2 + ((size_t)v * NH + h0 + r) * NH + o0 + c4);
    tile[r][c4 + 0] = d.x; tile[r][c4 + 1] = d.y;
    tile[r][c4 + 2] = d.z; tile[r][c4 + 3] = d.w;
    __syncthreads();
    ushort4 o;
    o.x = f32_to_bf16(tile[c4 + 0][r]);
    o.y = f32_to_bf16(tile[c4 + 1][r]);
    o.z = f32_to_bf16(tile[c4 + 2][r]);
    o.w = f32_to_bf16(tile[c4 + 3][r]);
    *(ushort4*)(W2T + ((size_t)v * NH + o0 + r) * NH + h0 + c4) = o;
}

// ---------------- Kernel B: weight-network GRN + softmax -> weights[tok][v] -------
__global__ __launch_bounds__(256) void k_weights(
    const float* __restrict__ x,
    const float* __restrict__ nW1, const float* __restrict__ nb1,
    const float* __restrict__ nW2, const float* __restrict__ nb2,
    const float* __restrict__ nWg, const float* __restrict__ nbg,
    const float* __restrict__ ng,  const float* __restrict__ nbe,
    float* __restrict__ wout_buf) {
    const int wv = threadIdx.x >> 6;
    const int lane = threadIdx.x & 63;
    const int tok = blockIdx.x * 4 + wv;
    const float xv = x[(size_t)tok * NV + lane];
    float acc1 = nb1[lane], accg = nbg[lane];
#pragma unroll 8
    for (int k = 0; k < 64; ++k) {
        const float xk = __shfl(xv, k);
        acc1 = fmaf(xk, nW1[k * 64 + lane], acc1);
        accg = fmaf(xk, nWg[k * 64 + lane], accg);
    }
    const float h  = felu(acc1);
    const float wg = fsigmoid(accg);
    float acc2 = nb2[lane];
#pragma unroll 8
    for (int k = 0; k < 64; ++k) {
        const float hk = __shfl(h, k);
        acc2 = fmaf(hk, nW2[k * 64 + lane], acc2);
    }
    const float pre = xv + wg * acc2;
    float s = pre;
#pragma unroll
    for (int m = 32; m >= 1; m >>= 1) s += __shfl_xor(s, m);
    const float mu = s * (1.0f / 64.0f);
    const float dd = pre - mu;
    float s2 = dd * dd;
#pragma unroll
    for (int m = 32; m >= 1; m >>= 1) s2 += __shfl_xor(s2, m);
    const float inv = rsqrtf(s2 * (1.0f / 64.0f) + LN_EPS);
    const float wln = dd * inv * ng[lane] + nbe[lane];
    float mx = wln;
#pragma unroll
    for (int m = 32; m >= 1; m >>= 1) mx = fmaxf(mx, __shfl_xor(mx, m));
    const float e = __expf(wln - mx);
    float se = e;
#pragma unroll
    for (int m = 32; m >= 1; m >>= 1) se += __shfl_xor(se, m);
    wout_buf[(size_t)tok * NV + lane] = e / se;
}

__device__ __forceinline__ const float* row_ptr(int r, const float* W1, const float* b1,
                                                const float* Wg, const float* bg,
                                                const float* Ws, const float* bs,
                                                const float* b2, const float* g1,
                                                const float* be1) {
    switch (r) {
        case 0: return W1; case 1: return b1; case 2: return Wg; case 3: return bg;
        case 4: return Ws; case 5: return bs; case 6: return b2; case 7: return g1;
        default: return be1;
    }
}

// ---------------- Kernel C: fused per-var GRN (MFMA) + weighted accumulate --------
// grid 512 (bid&7 = vgroup/XCD; bid>>3 = 64-token tile). 256 thr = 4 waves; each
// wave = 16 tokens x ALL 256 cols (no A-gen duplication; LN fully wave-local).
// Per var: A-frag (1/ks) in regs; B panel (16KB) LDS double-buffered via
// global_load_lds; 8 ks x 16 MFMA(16x16x32); epilogue gate/skip/LN in-wave.
__global__ __launch_bounds__(256, 2) void k_main(
    const float* __restrict__ x, const unsigned short* __restrict__ W2T,
    const float* __restrict__ W1, const float* __restrict__ b1,
    const float* __restrict__ Wg, const float* __restrict__ bg,
    const float* __restrict__ Ws, const float* __restrict__ bs,
    const float* __restrict__ b2, const float* __restrict__ g1,
    const float* __restrict__ be1, const float* __restrict__ wgts,
    float* __restrict__ partials,   // [8][NTOK][NH] or nullptr
    float* __restrict__ outacc) {   // atomic fallback
    __shared__ u32x4 sB[2][1024];     // 2 x 16KB B K-step panel, slot-swizzled
    __shared__ float sRB[2][9][256];  // 2 x {W1,b1,Wg,bg,Ws,bs,b2,g1,be1}
    __shared__ float sX[64][9];       // [tok][var] (+pad)
    __shared__ float sW[64][9];

    const int tid  = threadIdx.x;
    const int wid  = tid >> 6, lane = tid & 63;  // wid = token-group
    const int c    = lane & 15, kg = lane >> 4;
    const int bid  = blockIdx.x;
    const int vg   = bid & 7, tt = bid >> 3;
    const int t0   = tt * 64, vbase = vg * 8;

    const float* r0p = row_ptr(2 * wid,     W1, b1, Wg, bg, Ws, bs, b2, g1, be1);
    const float* r1p = row_ptr(2 * wid + 1, W1, b1, Wg, bg, Ws, bs, b2, g1, be1);

    // per-thread B-stage constants (4 chunks): idx -> (o, slot) -> src/dst offsets
    int bsrc[4], bdst[4];
#pragma unroll
    for (int q = 0; q < 4; ++q) {
        const int idx = wid * 256 + q * 64 + lane;
        const int o = idx >> 2, sl = idx & 3;
        const int s = (sl - (o >> 1)) & 3;
        bsrc[q] = o * NH + s * 8;   // element offset within the var's W2T
        bdst[q] = idx * 16;         // byte offset within panel
    }

    // ---- prologue ----
    const unsigned short* W2Tv0 = W2T + (size_t)vbase * (NH * NH);
    gload16(W2Tv0 + bsrc[0], (char*)sB[0] + bdst[0]);
    gload16(W2Tv0 + bsrc[1], (char*)sB[0] + bdst[1]);
    gload16(W2Tv0 + bsrc[2], (char*)sB[0] + bdst[2]);
    gload16(W2Tv0 + bsrc[3], (char*)sB[0] + bdst[3]);
    gload16(r0p + (size_t)vbase * NH + lane * 4, (char*)sRB[0] + (2 * wid) * 1024);
    gload16(r1p + (size_t)vbase * NH + lane * 4, (char*)sRB[0] + (2 * wid + 1) * 1024);
    if (wid == 0)
        gload16(be1 + (size_t)vbase * NH + lane * 4, (char*)sRB[0] + 8 * 1024);
#pragma unroll
    for (int e = 0; e < 2; ++e) {
        const int ee = tid + e * 256;
        const int row = ee >> 3, cc = ee & 7;
        sX[row][cc] = x[(size_t)(t0 + row) * NV + vbase + cc];
        sW[row][cc] = wgts[(size_t)(t0 + row) * NV + vbase + cc];
    }
    __syncthreads();

    // b128 B-frag read base: row o = f*16+c, slot rotated -> balanced banks
    const int rdbase = c * 64 + (((kg + (c >> 1)) & 3) << 4);
    const f32x4 fzero = {0.f, 0.f, 0.f, 0.f};

    f32x4 wacc[16];
#pragma unroll
    for (int f = 0; f < 16; ++f) wacc[f] = fzero;

#pragma unroll 1
    for (int vi = 0; vi < 8; ++vi) {
        const int rcur = vi & 1;
        const unsigned short* W2Tv = W2T + (size_t)(vbase + vi) * (NH * NH);
        const float xv = sX[wid * 16 + c][vi];

        f32x4 acc[16];
#pragma unroll
        for (int f = 0; f < 16; ++f) acc[f] = fzero;

#pragma unroll 1
        for (int ks = 0; ks < 8; ++ks) {
            const int cb = ks & 1;
            // -- prefetch next var's param rows (at ks==1: after ks0-end barrier,
            //    so no wave can still be reading sRB[rcur] in its prior epilogue) --
            if (ks == 1 && vi < 7) {
                gload16(r0p + (size_t)(vbase + vi + 1) * NH + lane * 4,
                        (char*)sRB[rcur ^ 1] + (2 * wid) * 1024);
                gload16(r1p + (size_t)(vbase + vi + 1) * NH + lane * 4,
                        (char*)sRB[rcur ^ 1] + (2 * wid + 1) * 1024);
                if (wid == 0)
                    gload16(be1 + (size_t)(vbase + vi + 1) * NH + lane * 4,
                            (char*)sRB[rcur ^ 1] + 8 * 1024);
            }
            // -- prefetch next B panel --
            if (ks < 7 || vi < 7) {
                const unsigned short* Wsrc =
                    (ks < 7) ? (W2Tv + (ks + 1) * 32) : (W2Tv + NH * NH);
                char* bb1 = (char*)sB[cb ^ 1];
                gload16(Wsrc + bsrc[0], bb1 + bdst[0]);
                gload16(Wsrc + bsrc[1], bb1 + bdst[1]);
                gload16(Wsrc + bsrc[2], bb1 + bdst[2]);
                gload16(Wsrc + bsrc[3], bb1 + bdst[3]);
            }
            // -- A-frag gen (one 16x32 tile per wave) --
            const int k0 = ks * 32 + kg * 8;
            const float4 wA = *(const float4*)&sRB[rcur][0][k0];
            const float4 wB = *(const float4*)&sRB[rcur][0][k0 + 4];
            const float4 bA = *(const float4*)&sRB[rcur][1][k0];
            const float4 bB = *(const float4*)&sRB[rcur][1][k0 + 4];
            u32x4 ap;
            {
                const float z0 = fmaf(xv, wA.x, bA.x), z1 = fmaf(xv, wA.y, bA.y);
                const float z2 = fmaf(xv, wA.z, bA.z), z3 = fmaf(xv, wA.w, bA.w);
                const float z4 = fmaf(xv, wB.x, bB.x), z5 = fmaf(xv, wB.y, bB.y);
                const float z6 = fmaf(xv, wB.z, bB.z), z7 = fmaf(xv, wB.w, bB.w);
                ap[0] = pack_bf16x2(felu(z0), felu(z1));
                ap[1] = pack_bf16x2(felu(z2), felu(z3));
                ap[2] = pack_bf16x2(felu(z4), felu(z5));
                ap[3] = pack_bf16x2(felu(z6), felu(z7));
            }
            const short8 af = __builtin_bit_cast(short8, ap);
            const char* bb = (const char*)sB[cb] + rdbase;
            __builtin_amdgcn_s_setprio(1);
#pragma unroll
            for (int f = 0; f < 16; ++f) {
                const short8 bf = __builtin_bit_cast(short8, *(const u32x4*)(bb + (f << 10)));
                acc[f] = __builtin_amdgcn_mfma_f32_16x16x32_bf16(af, bf, acc[f], 0, 0, 0);
            }
            __builtin_amdgcn_s_setprio(0);
            __syncthreads();   // drains prefetch + buffer swap
        }

        // -- epilogue: gate/skip/sigmoid + wave-local LN + weighted accumulate --
        float xr[4], wv_[4];
#pragma unroll
        for (int r = 0; r < 4; ++r) {
            const int tl = wid * 16 + kg * 4 + r;
            xr[r]  = sX[tl][vi];
            wv_[r] = sW[tl][vi];
        }
        float ps[4] = {}, pq[4] = {};
        float gv[16], bev[16];
#pragma unroll
        for (int f = 0; f < 16; ++f) {
            const int h = f * 16 + c;
            const float Wg_ = sRB[rcur][2][h], bg_ = sRB[rcur][3][h];
            const float Ws_ = sRB[rcur][4][h], bs_ = sRB[rcur][5][h];
            const float b2_ = sRB[rcur][6][h];
            gv[f] = sRB[rcur][7][h]; bev[f] = sRB[rcur][8][h];
#pragma unroll
            for (int r = 0; r < 4; ++r) {
                const float y = fmaf(xr[r], Ws_, bs_) +
                                fsigmoid(fmaf(xr[r], Wg_, bg_)) * (acc[f][r] + b2_);
                acc[f][r] = y;
                ps[r] += y;
                pq[r] = fmaf(y, y, pq[r]);
            }
        }
#pragma unroll
        for (int m = 1; m <= 8; m <<= 1)
#pragma unroll
            for (int r = 0; r < 4; ++r) {
                ps[r] += __shfl_xor(ps[r], m);
                pq[r] += __shfl_xor(pq[r], m);
            }
#pragma unroll
        for (int r = 0; r < 4; ++r) {
            const float mu = ps[r] * (1.0f / 256.0f);
            const float vr = fmaf(-mu, mu, pq[r] * (1.0f / 256.0f));
            const float iv = rsqrtf(vr + LN_EPS);
            const float wiv = wv_[r] * iv;
#pragma unroll
            for (int f = 0; f < 16; ++f)
                wacc[f][r] = fmaf(wiv * (acc[f][r] - mu), gv[f],
                                  fmaf(wv_[r], bev[f], wacc[f][r]));
        }
    }

    // -- write per-vgroup partials --
    const int tokb = t0 + wid * 16 + kg * 4;
    if (partials) {
        float* P = partials + (size_t)vg * NTOK * NH;
#pragma unroll
        for (int r = 0; r < 4; ++r) {
            float* rowp = P + (size_t)(tokb + r) * NH + c;
#pragma unroll
            for (int f = 0; f < 16; ++f) rowp[f * 16] = wacc[f][r];
        }
    } else {
#pragma unroll
        for (int r = 0; r < 4; ++r) {
            float* rowp = outacc + (size_t)(tokb + r) * NH + c;
#pragma unroll
            for (int f = 0; f < 16; ++f) atomicAdd(&rowp[f * 16], wacc[f][r]);
        }
    }
}

// ---------------- Kernel D: sum the 8 vgroup partials ----------------
__global__ __launch_bounds__(256) void k_reduce(const float* __restrict__ P,
                                                float* __restrict__ out) {
    const size_t i = ((size_t)blockIdx.x * 256 + threadIdx.x);
    const f32x4* P4 = (const f32x4*)P;
    f32x4 s = P4[i];
#pragma unroll
    for (int sl = 1; sl < 8; ++sl) s += P4[(size_t)sl * (NTOK * NH / 4) + i];
    ((f32x4*)out)[i] = s;
}

extern "C" void kernel_launch(void* const* d_in, const int* in_sizes, int n_in,
                              void* d_out, int out_size, void* d_ws, size_t ws_size,
                              hipStream_t stream) {
    const float* x   = (const float*)d_in[0];
    const float* W1  = (const float*)d_in[1];
    const float* b1  = (const float*)d_in[2];
    const float* W2  = (const float*)d_in[3];
    const float* b2  = (const float*)d_in[4];
    const float* Wg  = (const float*)d_in[5];
    const float* bg  = (const float*)d_in[6];
    const float* Ws  = (const float*)d_in[7];
    const float* bs  = (const float*)d_in[8];
    const float* g1  = (const float*)d_in[9];
    const float* be1 = (const float*)d_in[10];
    const float* nW1 = (const float*)d_in[11];
    const float* nb1 = (const float*)d_in[12];
    const float* nW2 = (const float*)d_in[13];
    const float* nb2 = (const float*)d_in[14];
    const float* nWg = (const float*)d_in[15];
    const float* nbg = (const float*)d_in[16];
    const float* ng  = (const float*)d_in[17];
    const float* nbe = (const float*)d_in[18];
    float* out = (float*)d_out;

    // ws layout: [0,1MB) weights | [1MB,9MB) W2T bf16 | [9MB,41MB) partials
    char* ws = (char*)d_ws;
    float* ws_wgt = (float*)ws;
    unsigned short* ws_W2T = (unsigned short*)(ws + (1 << 20));
    const size_t part_off = (size_t)9 << 20;
    const size_t part_bytes = (size_t)8 * NTOK * NH * 4;
    const bool use_part = ws_size >= part_off + part_bytes;
    float* ws_part = use_part ? (float*)(ws + part_off) : nullptr;

    k_w2t<<<dim3(64 * 64), dim3(256), 0, stream>>>(W2, ws_W2T);
    k_weights<<<dim3(NTOK / 4), dim3(256), 0, stream>>>(x, nW1, nb1, nW2, nb2,
                                                        nWg, nbg, ng, nbe, ws_wgt);
    if (!use_part) hipMemsetAsync(d_out, 0, (size_t)out_size * 4, stream);
    k_main<<<dim3(512), dim3(256), 0, stream>>>(x, ws_W2T, W1, b1, Wg, bg, Ws, bs,
                                                b2, g1, be1, ws_wgt, ws_part, out);
    if (use_part)
        k_reduce<<<dim3(NTOK * NH / 4 / 256), dim3(256), 0, stream>>>(ws_part, out);
}